// Round 8
// baseline (250.943 us; speedup 1.0000x reference)
//
#include <hip/hip_runtime.h>

// Problem constants (from reference)
#define NB     32      // B
#define NPTS   2048    // N
#define KNN    16      // K
#define FIN    32      // F_IN
#define FOUT   64      // F_OUT

typedef __attribute__((ext_vector_type(8))) short bf16x8;
typedef __attribute__((ext_vector_type(4))) float f32x4;

// RNE float->bf16 pack
__device__ inline unsigned bf16pk(float lo, float hi) {
    unsigned a = __float_as_uint(lo), b = __float_as_uint(hi);
    a = (a + 0x7fffu + ((a >> 16) & 1u)) >> 16;
    b = (b + 0x7fffu + ((b >> 16) & 1u)) >> 16;
    return (a & 0xffffu) | (b << 16);
}

// ---------------------------------------------------------------------------
// Kernel 1: exact 16-NN per point (R5/R7 version, verbatim — passed on HW).
// ---------------------------------------------------------------------------
#define CH   4
#define CHL  (NPTS / CH)
#define QG   2
#define BT   (QG * CH * 64)

#define CEA(x, y) { float _t = fminf(x, y); y = fmaxf(x, y); x = _t; }
#define CED(x, y) { float _t = fmaxf(x, y); y = fminf(x, y); x = _t; }

#define BMERGE16(dk) \
    CEA(dk[0],dk[8])  CEA(dk[1],dk[9])  CEA(dk[2],dk[10]) CEA(dk[3],dk[11]) \
    CEA(dk[4],dk[12]) CEA(dk[5],dk[13]) CEA(dk[6],dk[14]) CEA(dk[7],dk[15]) \
    CEA(dk[0],dk[4])  CEA(dk[1],dk[5])  CEA(dk[2],dk[6])  CEA(dk[3],dk[7])  \
    CEA(dk[8],dk[12]) CEA(dk[9],dk[13]) CEA(dk[10],dk[14]) CEA(dk[11],dk[15]) \
    CEA(dk[0],dk[2])  CEA(dk[1],dk[3])  CEA(dk[4],dk[6])  CEA(dk[5],dk[7])  \
    CEA(dk[8],dk[10]) CEA(dk[9],dk[11]) CEA(dk[12],dk[14]) CEA(dk[13],dk[15]) \
    CEA(dk[0],dk[1])  CEA(dk[2],dk[3])  CEA(dk[4],dk[5])  CEA(dk[6],dk[7])  \
    CEA(dk[8],dk[9])  CEA(dk[10],dk[11]) CEA(dk[12],dk[13]) CEA(dk[14],dk[15])

__global__ __launch_bounds__(BT) void knn_kernel(
    const float* __restrict__ pos, int* __restrict__ idx_out)
{
    __shared__ float4 P[NPTS];
    __shared__ float  V[QG * CH * KNN * 64];
    __shared__ int    CNTS[QG * CH * 64];

    const int b   = blockIdx.x >> 4;
    const int qgb = blockIdx.x & 15;
    const int t   = threadIdx.x;
    const int w   = t >> 6;
    const int qgl = w >> 2;
    const int ch  = w & 3;
    const int l   = t & 63;

    const float* pb = pos + (size_t)b * NPTS * 3;

    for (int r = 0; r < NPTS / BT; ++r) {
        int j = r * BT + t;
        float px = pb[j*3 + 0];
        float py = pb[j*3 + 1];
        float pz = pb[j*3 + 2];
        float sq = __fadd_rn(__fadd_rn(__fmul_rn(px,px), __fmul_rn(py,py)),
                             __fmul_rn(pz,pz));
        P[j] = make_float4(px, py, pz, sq);
    }
    __syncthreads();

    const int q = (qgb * QG + qgl) * 64 + l;
    const float4 me = P[q];

    float dk[KNN];
    #pragma unroll
    for (int s = 0; s < KNN; ++s) dk[s] = 1e30f;

    const int j0 = ch * CHL;
    for (int jb = 0; jb < CHL; jb += 8) {
        float a[8];
        #pragma unroll
        for (int i = 0; i < 8; ++i) {
            const int j = j0 + jb + i;
            const float4 c = P[j];
            float dot = __fadd_rn(__fadd_rn(__fmul_rn(me.x,c.x),
                                            __fmul_rn(me.y,c.y)),
                                  __fmul_rn(me.z,c.z));
            float d2 = __fsub_rn(__fadd_rn(me.w, c.w), __fmul_rn(2.0f, dot));
            a[i] = (j == q) ? 1e30f : d2;
        }
        CED(a[0],a[1]) CED(a[2],a[3]) CED(a[4],a[5]) CED(a[6],a[7])
        CED(a[0],a[2]) CED(a[1],a[3]) CED(a[4],a[6]) CED(a[5],a[7])
        CED(a[1],a[2]) CED(a[5],a[6])
        CED(a[0],a[4]) CED(a[1],a[5]) CED(a[2],a[6]) CED(a[3],a[7])
        CED(a[2],a[4]) CED(a[3],a[5])
        CED(a[1],a[2]) CED(a[3],a[4]) CED(a[5],a[6])
        #pragma unroll
        for (int i = 0; i < 8; ++i) dk[8+i] = fminf(dk[8+i], a[i]);
        BMERGE16(dk)
    }

    #pragma unroll
    for (int s = 0; s < KNN; ++s)
        V[((qgl * CH + ch) * KNN + s) * 64 + l] = dk[s];
    __syncthreads();

    for (int c2 = 0; c2 < CH; ++c2) {
        if (c2 == ch) continue;
        float v[KNN];
        #pragma unroll
        for (int s2 = 0; s2 < KNN; ++s2)
            v[s2] = V[((qgl * CH + c2) * KNN + s2) * 64 + l];
        #pragma unroll
        for (int s = 0; s < KNN; ++s) dk[s] = fminf(dk[s], v[KNN-1-s]);
        BMERGE16(dk)
    }
    const float tthr = dk[KNN-1];
    __syncthreads();

    int* JL = (int*)V;
    const int base = (qgl * CH + ch) * KNN * 64;
    int cntS = 0, cntT = 0;
    for (int jj = 0; jj < CHL; ++jj) {
        const int j = j0 + jj;
        const float4 c = P[j];
        float dot = __fadd_rn(__fadd_rn(__fmul_rn(me.x,c.x),
                                        __fmul_rn(me.y,c.y)),
                              __fmul_rn(me.z,c.z));
        float d2 = __fsub_rn(__fadd_rn(me.w, c.w), __fmul_rn(2.0f, dot));
        d2 = (j == q) ? 1e30f : d2;
        if (d2 <= tthr) {
            if (d2 < tthr) {
                if (cntS + cntT >= KNN) --cntT;
                JL[base + cntS * 64 + l] = j;
                ++cntS;
            } else if (cntS + cntT < KNN) {
                JL[base + (KNN - 1 - cntT) * 64 + l] = j;
                ++cntT;
            }
        }
    }
    CNTS[(qgl * CH + ch) * 64 + l] = cntS | (cntT << 16);
    __syncthreads();

    if (ch == 0) {
        int* o = idx_out + ((size_t)b * NPTS + q) * KNN;
        int outc = 0;
        for (int c2 = 0; c2 < CH; ++c2) {
            int cs = CNTS[(qgl * CH + c2) * 64 + l] & 0xffff;
            for (int s2 = 0; s2 < cs && outc < KNN; ++s2)
                o[outc++] = JL[((qgl * CH + c2) * KNN + s2) * 64 + l];
        }
        for (int c2 = 0; c2 < CH && outc < KNN; ++c2) {
            int ct = CNTS[(qgl * CH + c2) * 64 + l] >> 16;
            for (int s2 = 0; s2 < ct && outc < KNN; ++s2)
                o[outc++] = JL[((qgl * CH + c2) * KNN + (KNN - 1 - s2)) * 64 + l];
        }
    }
}

// ---------------------------------------------------------------------------
// Kernel 2: MFMA edge MLP, COMPACT. One wave per 16-node tile.
// No LDS A-tile: lane (g=lane>>4, c15=lane&15) gathers its OWN A-fragment
// directly — row = neighbor c15 of the node, k-slice g*8..g*8+7 (32 B
// contiguous, 2x float4) — packs to bf16 in-register. Node loop kept ROLLED
// (small I$ footprint) with a depth-1 manual prefetch. Math is bitwise
// identical to the R7-passing MLP (same loads, same pk, same MFMA, same
// reduction & epilogue).
// ---------------------------------------------------------------------------
#define MLP_WAVES 4
#define ZROW 65
#define ZWORDS (16 * ZROW)

__global__ __launch_bounds__(256) void edge_mlp_kernel(
    const float* __restrict__ x, const int* __restrict__ idxws,
    const float* __restrict__ W_edge, const float* __restrict__ b_edge,
    const float* __restrict__ W_nn, const float* __restrict__ b_nn,
    float* __restrict__ out)
{
    __shared__ float Zbuf[MLP_WAVES][ZWORDS];

    const int lane = threadIdx.x & 63;
    const int w    = threadIdx.x >> 6;
    const int c15  = lane & 15;
    const int g    = lane >> 4;

    float* Zw = &Zbuf[w][0];

    const int tile  = blockIdx.x * MLP_WAVES + w;
    const int n0    = tile * 16;
    const int gbase = n0 & ~(NPTS - 1);

    // B-fragments (bf16) + epilogue constants
    int4 Bhi[4], Bd[4], Bn[4];
    #pragma unroll
    for (int f = 0; f < 4; ++f) {
        const int col = 16 * f + c15;
        unsigned ph[4], pd[4], pn[4];
        #pragma unroll
        for (int d = 0; d < 4; ++d) {
            const int k0 = g * 8 + 2 * d;
            float h0 = W_edge[(FIN + k0)     * FOUT + col];
            float h1 = W_edge[(FIN + k0 + 1) * FOUT + col];
            float l0 = W_edge[k0       * FOUT + col] - h0;
            float l1 = W_edge[(k0 + 1) * FOUT + col] - h1;
            float n0f = W_nn[k0       * FOUT + col];
            float n1f = W_nn[(k0 + 1) * FOUT + col];
            ph[d] = bf16pk(h0, h1);
            pd[d] = bf16pk(l0, l1);
            pn[d] = bf16pk(n0f, n1f);
        }
        Bhi[f] = make_int4(ph[0], ph[1], ph[2], ph[3]);
        Bd[f]  = make_int4(pd[0], pd[1], pd[2], pd[3]);
        Bn[f]  = make_int4(pn[0], pn[1], pn[2], pn[3]);
    }
    float beF[4], bnF[4];
    #pragma unroll
    for (int f = 0; f < 4; ++f) {
        beF[f] = b_edge[16 * f + c15];
        bnF[f] = b_nn[16 * f + c15];
    }

    const f32x4 zf = {0.f, 0.f, 0.f, 0.f};

    // ---- Phase 1: base/skip via MFMA over the 16 x_i rows (direct A-frag) --
    f32x4 baseF[4], skipF[4];
    {
        const float* rp = x + (size_t)(n0 + c15) * FIN + g * 8;
        float4 v0 = *(const float4*)rp;
        float4 v1 = *(const float4*)(rp + 4);
        int4 pk = make_int4(bf16pk(v0.x, v0.y), bf16pk(v0.z, v0.w),
                            bf16pk(v1.x, v1.y), bf16pk(v1.z, v1.w));
        bf16x8 afi = *(bf16x8*)&pk;
        #pragma unroll
        for (int f = 0; f < 4; ++f) {
            baseF[f] = __builtin_amdgcn_mfma_f32_16x16x32_bf16(
                afi, *(bf16x8*)&Bd[f], zf, 0, 0, 0);
            skipF[f] = __builtin_amdgcn_mfma_f32_16x16x32_bf16(
                afi, *(bf16x8*)&Bn[f], zf, 0, 0, 0);
        }
    }

    // ---- Phase 2: rolled node loop, direct A-frag gather, depth-1 prefetch -
    int nb0 = idxws[(size_t)n0 * KNN + c15];
    const float* rpp = x + (size_t)(gbase + nb0) * FIN + g * 8;
    float4 pv0 = *(const float4*)rpp;
    float4 pv1 = *(const float4*)(rpp + 4);

    #pragma unroll 1
    for (int i = 0; i < 16; ++i) {
        float4 c0 = pv0, c1 = pv1;
        if (i < 15) {
            int nb = idxws[(size_t)(n0 + i + 1) * KNN + c15];
            const float* rp = x + (size_t)(gbase + nb) * FIN + g * 8;
            pv0 = *(const float4*)rp;
            pv1 = *(const float4*)(rp + 4);
        }
        int4 pk = make_int4(bf16pk(c0.x, c0.y), bf16pk(c0.z, c0.w),
                            bf16pk(c1.x, c1.y), bf16pk(c1.z, c1.w));
        bf16x8 af = *(bf16x8*)&pk;

        float rmax[4];
        #pragma unroll
        for (int f = 0; f < 4; ++f) {
            f32x4 z = __builtin_amdgcn_mfma_f32_16x16x32_bf16(
                af, *(bf16x8*)&Bhi[f], zf, 0, 0, 0);
            float m = fmaxf(fmaxf(z[0], z[1]), fmaxf(z[2], z[3]));
            m = fmaxf(m, __shfl_xor(m, 16));
            m = fmaxf(m, __shfl_xor(m, 32));
            rmax[f] = m;
        }
        float zv = (g == 0) ? rmax[0] : (g == 1) ? rmax[1]
                 : (g == 2) ? rmax[2] : rmax[3];
        Zw[i * ZROW + 16 * g + c15] = zv;
    }

    // ---- Phase 3: epilogue + store (D layout: node=(g*4+reg), col=16f+c15) -
    #pragma unroll
    for (int f = 0; f < 4; ++f) {
        #pragma unroll
        for (int reg = 0; reg < 4; ++reg) {
            const int nd = g * 4 + reg;
            float zmax = Zw[nd * ZROW + 16 * f + c15];
            float e  = fmaxf(zmax + baseF[f][reg] + beF[f], 0.f);
            float sk = fmaxf(skipF[f][reg] + bnF[f], 0.f);
            out[(size_t)(n0 + nd) * FOUT + 16 * f + c15] = e + sk;
        }
    }
}

// ---------------------------------------------------------------------------
extern "C" void kernel_launch(void* const* d_in, const int* in_sizes, int n_in,
                              void* d_out, int out_size, void* d_ws, size_t ws_size,
                              hipStream_t stream) {
    const float* x      = (const float*)d_in[0];
    const float* pos    = (const float*)d_in[1];
    const float* W_edge = (const float*)d_in[2];
    const float* b_edge = (const float*)d_in[3];
    const float* W_nn   = (const float*)d_in[4];
    const float* b_nn   = (const float*)d_in[5];

    int*   idxws = (int*)d_ws;              // 32*2048*16 ints = 4 MB
    float* outp  = (float*)d_out;

    knn_kernel<<<NB * 16, BT, 0, stream>>>(pos, idxws);
    edge_mlp_kernel<<<(NB * NPTS) / (MLP_WAVES * 16), 256, 0, stream>>>(
        x, idxws, W_edge, b_edge, W_nn, b_nn, outp);
}

// Round 9
// 242.904 us; speedup vs baseline: 1.0331x; 1.0331x over previous
//
#include <hip/hip_runtime.h>

// Problem constants (from reference)
#define NB     32      // B
#define NPTS   2048    // N
#define KNN    16      // K
#define FIN    32      // F_IN
#define FOUT   64      // F_OUT

typedef __attribute__((ext_vector_type(8))) short bf16x8;
typedef __attribute__((ext_vector_type(4))) float f32x4;

// RNE float->bf16 pack
__device__ inline unsigned bf16pk(float lo, float hi) {
    unsigned a = __float_as_uint(lo), b = __float_as_uint(hi);
    a = (a + 0x7fffu + ((a >> 16) & 1u)) >> 16;
    b = (b + 0x7fffu + ((b >> 16) & 1u)) >> 16;
    return (a & 0xffffu) | (b << 16);
}

// ---------------------------------------------------------------------------
// FUSED kernel: phase A = exact 16-NN (R7 code, verbatim semantics) writing
// neighbor lists to d_ws; __syncthreads (block-scope fence incl. global);
// phase B = MFMA edge MLP (R8 code) for the SAME 128 nodes, 8 waves x 16.
// Zbuf for the MLP aliases the dead P buffer (barrier-separated).
// One dispatch total — tests the fixed-overhead theory for the missing 78us.
// ---------------------------------------------------------------------------
#define CH   4
#define CHL  (NPTS / CH)
#define QG   2
#define BT   (QG * CH * 64)

#define CEA(x, y) { float _t = fminf(x, y); y = fmaxf(x, y); x = _t; }
#define CED(x, y) { float _t = fmaxf(x, y); y = fminf(x, y); x = _t; }

#define BMERGE16(dk) \
    CEA(dk[0],dk[8])  CEA(dk[1],dk[9])  CEA(dk[2],dk[10]) CEA(dk[3],dk[11]) \
    CEA(dk[4],dk[12]) CEA(dk[5],dk[13]) CEA(dk[6],dk[14]) CEA(dk[7],dk[15]) \
    CEA(dk[0],dk[4])  CEA(dk[1],dk[5])  CEA(dk[2],dk[6])  CEA(dk[3],dk[7])  \
    CEA(dk[8],dk[12]) CEA(dk[9],dk[13]) CEA(dk[10],dk[14]) CEA(dk[11],dk[15]) \
    CEA(dk[0],dk[2])  CEA(dk[1],dk[3])  CEA(dk[4],dk[6])  CEA(dk[5],dk[7])  \
    CEA(dk[8],dk[10]) CEA(dk[9],dk[11]) CEA(dk[12],dk[14]) CEA(dk[13],dk[15]) \
    CEA(dk[0],dk[1])  CEA(dk[2],dk[3])  CEA(dk[4],dk[5])  CEA(dk[6],dk[7])  \
    CEA(dk[8],dk[9])  CEA(dk[10],dk[11]) CEA(dk[12],dk[13]) CEA(dk[14],dk[15])

__global__ __launch_bounds__(BT) void knn_mlp_kernel(
    const float* __restrict__ pos, const float* __restrict__ x,
    const float* __restrict__ W_edge, const float* __restrict__ b_edge,
    const float* __restrict__ W_nn, const float* __restrict__ b_nn,
    int* __restrict__ idxws, float* __restrict__ out)
{
    __shared__ float4 P[NPTS];               // 32 KB; reused as Zbuf in phase B
    __shared__ float  V[QG * CH * KNN * 64]; // 32 KB; reused as int JL
    __shared__ int    CNTS[QG * CH * 64];    // 2 KB

    const int b   = blockIdx.x >> 4;
    const int qgb = blockIdx.x & 15;
    const int t   = threadIdx.x;
    const int w   = t >> 6;
    const int qgl = w >> 2;
    const int ch  = w & 3;
    const int l   = t & 63;

    // ======================= Phase A: exact 16-NN ==========================
    {
        const float* pb = pos + (size_t)b * NPTS * 3;
        for (int r = 0; r < NPTS / BT; ++r) {
            int j = r * BT + t;
            float px = pb[j*3 + 0];
            float py = pb[j*3 + 1];
            float pz = pb[j*3 + 2];
            float sq = __fadd_rn(__fadd_rn(__fmul_rn(px,px), __fmul_rn(py,py)),
                                 __fmul_rn(pz,pz));
            P[j] = make_float4(px, py, pz, sq);
        }
        __syncthreads();

        const int q = (qgb * QG + qgl) * 64 + l;
        const float4 me = P[q];

        float dk[KNN];
        #pragma unroll
        for (int s = 0; s < KNN; ++s) dk[s] = 1e30f;

        const int j0 = ch * CHL;
        for (int jb = 0; jb < CHL; jb += 8) {
            float a[8];
            #pragma unroll
            for (int i = 0; i < 8; ++i) {
                const int j = j0 + jb + i;
                const float4 c = P[j];
                float dot = __fadd_rn(__fadd_rn(__fmul_rn(me.x,c.x),
                                                __fmul_rn(me.y,c.y)),
                                      __fmul_rn(me.z,c.z));
                float d2 = __fsub_rn(__fadd_rn(me.w, c.w), __fmul_rn(2.0f, dot));
                a[i] = (j == q) ? 1e30f : d2;
            }
            CED(a[0],a[1]) CED(a[2],a[3]) CED(a[4],a[5]) CED(a[6],a[7])
            CED(a[0],a[2]) CED(a[1],a[3]) CED(a[4],a[6]) CED(a[5],a[7])
            CED(a[1],a[2]) CED(a[5],a[6])
            CED(a[0],a[4]) CED(a[1],a[5]) CED(a[2],a[6]) CED(a[3],a[7])
            CED(a[2],a[4]) CED(a[3],a[5])
            CED(a[1],a[2]) CED(a[3],a[4]) CED(a[5],a[6])
            #pragma unroll
            for (int i = 0; i < 8; ++i) dk[8+i] = fminf(dk[8+i], a[i]);
            BMERGE16(dk)
        }

        #pragma unroll
        for (int s = 0; s < KNN; ++s)
            V[((qgl * CH + ch) * KNN + s) * 64 + l] = dk[s];
        __syncthreads();

        for (int c2 = 0; c2 < CH; ++c2) {
            if (c2 == ch) continue;
            float v[KNN];
            #pragma unroll
            for (int s2 = 0; s2 < KNN; ++s2)
                v[s2] = V[((qgl * CH + c2) * KNN + s2) * 64 + l];
            #pragma unroll
            for (int s = 0; s < KNN; ++s) dk[s] = fminf(dk[s], v[KNN-1-s]);
            BMERGE16(dk)
        }
        const float tthr = dk[KNN-1];
        __syncthreads();

        int* JL = (int*)V;
        const int base = (qgl * CH + ch) * KNN * 64;
        int cntS = 0, cntT = 0;
        for (int jj = 0; jj < CHL; ++jj) {
            const int j = j0 + jj;
            const float4 c = P[j];
            float dot = __fadd_rn(__fadd_rn(__fmul_rn(me.x,c.x),
                                            __fmul_rn(me.y,c.y)),
                                  __fmul_rn(me.z,c.z));
            float d2 = __fsub_rn(__fadd_rn(me.w, c.w), __fmul_rn(2.0f, dot));
            d2 = (j == q) ? 1e30f : d2;
            if (d2 <= tthr) {
                if (d2 < tthr) {
                    if (cntS + cntT >= KNN) --cntT;
                    JL[base + cntS * 64 + l] = j;
                    ++cntS;
                } else if (cntS + cntT < KNN) {
                    JL[base + (KNN - 1 - cntT) * 64 + l] = j;
                    ++cntT;
                }
            }
        }
        CNTS[(qgl * CH + ch) * 64 + l] = cntS | (cntT << 16);
        __syncthreads();

        if (ch == 0) {
            int* o = idxws + ((size_t)b * NPTS + q) * KNN;
            int outc = 0;
            for (int c2 = 0; c2 < CH; ++c2) {
                int cs = CNTS[(qgl * CH + c2) * 64 + l] & 0xffff;
                for (int s2 = 0; s2 < cs && outc < KNN; ++s2)
                    o[outc++] = JL[((qgl * CH + c2) * KNN + s2) * 64 + l];
            }
            for (int c2 = 0; c2 < CH && outc < KNN; ++c2) {
                int ct = CNTS[(qgl * CH + c2) * 64 + l] >> 16;
                for (int s2 = 0; s2 < ct && outc < KNN; ++s2)
                    o[outc++] = JL[((qgl * CH + c2) * KNN + (KNN - 1 - s2)) * 64 + l];
            }
        }
        __syncthreads();   // idxws writes visible block-wide; P dead below
    }

    // ======================= Phase B: MFMA edge MLP ========================
    // 8 waves x 16 nodes = this block's 128-node slab. Zbuf aliases P.
    {
        const int lane = t & 63;
        const int c15  = lane & 15;
        const int g    = lane >> 4;

        float* Zw = &P[0].x + w * (16 * 64);   // 1024 floats per wave (32 KB tot)

        const int n0    = b * NPTS + qgb * 128 + w * 16;  // global node base
        const int gbase = b * NPTS;                        // batch start row

        // B-fragments (bf16) + epilogue constants
        int4 Bhi[4], Bd[4], Bn[4];
        #pragma unroll
        for (int f = 0; f < 4; ++f) {
            const int col = 16 * f + c15;
            unsigned ph[4], pd[4], pn[4];
            #pragma unroll
            for (int d = 0; d < 4; ++d) {
                const int k0 = g * 8 + 2 * d;
                float h0 = W_edge[(FIN + k0)     * FOUT + col];
                float h1 = W_edge[(FIN + k0 + 1) * FOUT + col];
                float l0 = W_edge[k0       * FOUT + col] - h0;
                float l1 = W_edge[(k0 + 1) * FOUT + col] - h1;
                float n0f = W_nn[k0       * FOUT + col];
                float n1f = W_nn[(k0 + 1) * FOUT + col];
                ph[d] = bf16pk(h0, h1);
                pd[d] = bf16pk(l0, l1);
                pn[d] = bf16pk(n0f, n1f);
            }
            Bhi[f] = make_int4(ph[0], ph[1], ph[2], ph[3]);
            Bd[f]  = make_int4(pd[0], pd[1], pd[2], pd[3]);
            Bn[f]  = make_int4(pn[0], pn[1], pn[2], pn[3]);
        }
        float beF[4], bnF[4];
        #pragma unroll
        for (int f = 0; f < 4; ++f) {
            beF[f] = b_edge[16 * f + c15];
            bnF[f] = b_nn[16 * f + c15];
        }

        const f32x4 zf = {0.f, 0.f, 0.f, 0.f};

        // Phase 1: base/skip via MFMA over the 16 x_i rows (direct A-frag)
        f32x4 baseF[4], skipF[4];
        {
            const float* rp = x + (size_t)(n0 + c15) * FIN + g * 8;
            float4 v0 = *(const float4*)rp;
            float4 v1 = *(const float4*)(rp + 4);
            int4 pk = make_int4(bf16pk(v0.x, v0.y), bf16pk(v0.z, v0.w),
                                bf16pk(v1.x, v1.y), bf16pk(v1.z, v1.w));
            bf16x8 afi = *(bf16x8*)&pk;
            #pragma unroll
            for (int f = 0; f < 4; ++f) {
                baseF[f] = __builtin_amdgcn_mfma_f32_16x16x32_bf16(
                    afi, *(bf16x8*)&Bd[f], zf, 0, 0, 0);
                skipF[f] = __builtin_amdgcn_mfma_f32_16x16x32_bf16(
                    afi, *(bf16x8*)&Bn[f], zf, 0, 0, 0);
            }
        }

        // Phase 2: rolled node loop, direct A-frag gather, depth-1 prefetch
        int nb0 = idxws[(size_t)n0 * KNN + c15];
        const float* rpp = x + (size_t)(gbase + nb0) * FIN + g * 8;
        float4 pv0 = *(const float4*)rpp;
        float4 pv1 = *(const float4*)(rpp + 4);

        #pragma unroll 1
        for (int i = 0; i < 16; ++i) {
            float4 c0 = pv0, c1 = pv1;
            if (i < 15) {
                int nb = idxws[(size_t)(n0 + i + 1) * KNN + c15];
                const float* rp = x + (size_t)(gbase + nb) * FIN + g * 8;
                pv0 = *(const float4*)rp;
                pv1 = *(const float4*)(rp + 4);
            }
            int4 pk = make_int4(bf16pk(c0.x, c0.y), bf16pk(c0.z, c0.w),
                                bf16pk(c1.x, c1.y), bf16pk(c1.z, c1.w));
            bf16x8 af = *(bf16x8*)&pk;

            float rmax[4];
            #pragma unroll
            for (int f = 0; f < 4; ++f) {
                f32x4 z = __builtin_amdgcn_mfma_f32_16x16x32_bf16(
                    af, *(bf16x8*)&Bhi[f], zf, 0, 0, 0);
                float m = fmaxf(fmaxf(z[0], z[1]), fmaxf(z[2], z[3]));
                m = fmaxf(m, __shfl_xor(m, 16));
                m = fmaxf(m, __shfl_xor(m, 32));
                rmax[f] = m;
            }
            float zv = (g == 0) ? rmax[0] : (g == 1) ? rmax[1]
                     : (g == 2) ? rmax[2] : rmax[3];
            Zw[i * 64 + 16 * g + c15] = zv;
        }

        // Phase 3: epilogue + store (D layout: node=(g*4+reg), col=16f+c15)
        #pragma unroll
        for (int f = 0; f < 4; ++f) {
            #pragma unroll
            for (int reg = 0; reg < 4; ++reg) {
                const int nd = g * 4 + reg;
                float zmax = Zw[nd * 64 + 16 * f + c15];
                float e  = fmaxf(zmax + baseF[f][reg] + beF[f], 0.f);
                float sk = fmaxf(skipF[f][reg] + bnF[f], 0.f);
                out[(size_t)(n0 + nd) * FOUT + 16 * f + c15] = e + sk;
            }
        }
    }
}

// ---------------------------------------------------------------------------
extern "C" void kernel_launch(void* const* d_in, const int* in_sizes, int n_in,
                              void* d_out, int out_size, void* d_ws, size_t ws_size,
                              hipStream_t stream) {
    const float* x      = (const float*)d_in[0];
    const float* pos    = (const float*)d_in[1];
    const float* W_edge = (const float*)d_in[2];
    const float* b_edge = (const float*)d_in[3];
    const float* W_nn   = (const float*)d_in[4];
    const float* b_nn   = (const float*)d_in[5];

    int*   idxws = (int*)d_ws;              // 32*2048*16 ints = 4 MB
    float* outp  = (float*)d_out;

    knn_mlp_kernel<<<NB * 16, BT, 0, stream>>>(
        pos, x, W_edge, b_edge, W_nn, b_nn, idxws, outp);
}